// Round 8
// baseline (2468.755 us; speedup 1.0000x reference)
//
#include <hip/hip_runtime.h>
#include <math.h>

#ifndef M_PI
#define M_PI 3.14159265358979323846
#endif

#define NXx   360
#define NXY   (NXx*NXx)
#define NTRc  32
#define NMEASc 256
#define NSTEPSc 640
#define NBCc  15
#define PADc  73
#define NVc   214

#define BROWS 45
#define NBANDS 8
#define NBLK  (NTRc*NBANDS)     // 256 blocks == 256 CUs
#define NTHREADS 832            // 810 active strip threads (9 strips x 90 groups)
#define NGrow (NXx/4)           // 90
#define NSTRIPT 810
#define LDSROWS 49
#define LDSFLOATS (2*LDSROWS*NXx)
#define NSLOT 4
#define HALO_PER (NSLOT*4*NXx)  // 4 slots x 4 rows x 360

#define C2f   1.3333334f
#define C3f  (-0.083333336f)
#define ADX2  0.11111111f
#define DT2f  0.04f
#define DTf   0.2f
#define DXf   0.6f

// native vector type for inline-asm "v" constraints (HIP float4 is a struct)
typedef float f32x4 __attribute__((ext_vector_type(4)));

// ---- system-coherent (sc0 sc1) transport: executes at chip coherence point,
// bypasses L1/L2 on both sides -> no buffer_wbl2 / buffer_inv fences needed.
__device__ __forceinline__ void store4_sys(float* p, float4 v) {
    f32x4 vv; vv.x = v.x; vv.y = v.y; vv.z = v.z; vv.w = v.w;
    asm volatile("global_store_dwordx4 %0, %1, off sc0 sc1" :: "v"(p), "v"(vv) : "memory");
}
__device__ __forceinline__ float4 load4_sys(const float* p) {
    f32x4 r;
    asm volatile("global_load_dwordx4 %0, %1, off sc0 sc1\n\ts_waitcnt vmcnt(0)"
                 : "=&v"(r) : "v"(p) : "memory");
    return make_float4(r.x, r.y, r.z, r.w);
}
__device__ __forceinline__ void storei_sys(int* p, int v) {
    asm volatile("global_store_dword %0, %1, off sc0 sc1" :: "v"(p), "v"(v) : "memory");
}
__device__ __forceinline__ int loadi_sys(const int* p) {
    int r;
    asm volatile("global_load_dword %0, %1, off sc0 sc1\n\ts_waitcnt vmcnt(0)"
                 : "=&v"(r) : "v"(p) : "memory");
    return r;
}
__device__ __forceinline__ void drain_vm() {
    asm volatile("s_waitcnt vmcnt(0)" ::: "memory");
}

__global__ void velmin_kernel(const float* __restrict__ v, float* __restrict__ velmin) {
    __shared__ float s[256];
    float m = 1.5f;
    for (int i = threadIdx.x; i < NVc*NVc; i += 256) m = fminf(m, v[i]);
    s[threadIdx.x] = m;
    __syncthreads();
    for (int o = 128; o > 0; o >>= 1) {
        if (threadIdx.x < o) s[threadIdx.x] = fminf(s[threadIdx.x], s[threadIdx.x+o]);
        __syncthreads();
    }
    if (threadIdx.x == 0) *velmin = s[0];
}

__global__ void coef_kernel(const float* __restrict__ v, const float* __restrict__ velmin_p,
                            float* __restrict__ alpha, float* __restrict__ kap) {
    int idx = blockIdx.x*256 + threadIdx.x;
    if (idx >= NXY) return;
    int i = idx / NXx, j = idx - i*NXx;
    float vc = 1.5f;
    if (i >= PADc && i < PADc+NVc && j >= PADc && j < PADc+NVc)
        vc = v[(i-PADc)*NVc + (j-PADc)];
    float v2 = vc*vc;
    float al = v2 * ADX2;
    float velmin = *velmin_p;
    const float a = (float)((NBCc-1)*0.6);
    float ks = 3.0f*velmin*9.2103405f/(2.0f*a);
    float damp = 0.0f;
    int k = -1;
    if (j >= NXx-NBCc)      k = j-(NXx-NBCc);
    else if (j < NBCc)      k = NBCc-1-j;
    else if (i >= NXx-NBCc) k = i-(NXx-NBCc);
    else if (i < NBCc)      k = NBCc-1-i;
    if (k >= 0) { float r = (float)k*DXf/a; damp = ks*r*r; }
    alpha[idx] = al;
    kap[idx]   = damp*DTf;
}

__global__ void beta_kernel(const float* __restrict__ v, const int* __restrict__ in_inds,
                            float* __restrict__ beta) {
    int tr = threadIdx.x;
    if (tr >= NTRc) return;
    int idx = in_inds[tr];
    int i = idx / NXx, j = idx - i*NXx;
    float vc = 1.5f;
    if (i >= PADc && i < PADc+NVc && j >= PADc && j < PADc+NVc)
        vc = v[(i-PADc)*NVc + (j-PADc)];
    beta[tr] = DT2f*vc*vc;
}

// Persistent LDS-resident kernel; vertical 5-row register-blocked strips.
// Thread (s,jg), s=0..8, jg=0..89: owns rows 5s..5s+4, cells 4jg..4jg+3.
// Rolling C-column window -> each cur value read ONCE (29 b128/strip vs 45).
// Fence-free sc0sc1 halo transport, 4 slots, edge-first (strips 0,8 in
// phase A, publish halos, flag; interior strips after; poll hides under
// interior compute).
__global__ __launch_bounds__(NTHREADS, 4) void persist_kernel(
    const float* __restrict__ alpha, const float* __restrict__ kap,
    const float* __restrict__ beta, const float* __restrict__ src,
    const int* __restrict__ meas_inds, const int* __restrict__ in_inds,
    int* flags, float* haloG, float* __restrict__ out)
{
    extern __shared__ float lds[];
    const int tid  = threadIdx.x;
    const int b    = blockIdx.x;
    const int tr   = b >> 3, band = b & 7;
    const int band0 = band*BROWS;
    const int up = (tr<<3) | ((band+7)&7);
    const int dn = (tr<<3) | ((band+1)&7);

    float* buf0 = lds;
    float* buf1 = lds + LDSROWS*NXx;

    for (int i = tid; i < LDSFLOATS; i += NTHREADS) lds[i] = 0.0f;

    const float betaV = beta[tr];
    const int sCell = in_inds[tr];
    const int sr = sCell/NXx, sc = sCell - sr*NXx;

    const bool isStrip = (tid < NSTRIPT);
    const int s  = isStrip ? (tid/NGrow) : 0;
    const int jg = isStrip ? (tid - s*NGrow) : 0;
    const int r0 = 5*s;
    const bool isEdge = isStrip && (s == 0 || s == 8);
    const int jgm = (jg==0) ? NGrow-1 : jg-1;
    const int jgp = (jg==NGrow-1) ? 0 : jg+1;

    float4 Ar[5], Kr[5];
    int qrow = -1, qcomp = 0;
    if (isStrip) {
#pragma unroll
        for (int k = 0; k < 5; ++k) {
            int gi = (band0 + r0 + k)*NXx + jg*4;
            Ar[k] = *(const float4*)(alpha + gi);
            Kr[k] = *(const float4*)(kap + gi);
        }
        if (sr >= band0+r0 && sr < band0+r0+5 && (sc>>2) == jg) {
            qrow = sr - (band0+r0); qcomp = sc & 3;
        }
    } else {
#pragma unroll
        for (int k = 0; k < 5; ++k) { Ar[k] = make_float4(0,0,0,0); Kr[k] = Ar[k]; }
    }

    bool mOwn = false; int mOff = 0;
    float* outP = out + ((size_t)tr*NSTEPSc)*NMEASc + tid;
    if (tid < NMEASc) {
        int mi = meas_inds[tid]; int row = mi/NXx, col = mi - row*NXx;
        if (row >= band0 && row < band0+BROWS) { mOwn = true; mOff = (row-band0+2)*NXx + col; }
    }

    float* myHalo = haloG + (size_t)b*HALO_PER;
    float* upHalo = haloG + (size_t)up*HALO_PER;
    float* dnHalo = haloG + (size_t)dn*HALO_PER;

    __syncthreads();

// one 5-row strip: rolling column window, L/R/Pp per row, write, opt. halo.
#define STRIP_COMPUTE(DOHALO) { \
    const int base = r0*NGrow + jg; \
    float4 cm2 = cur4[base]; \
    float4 cm1 = cur4[base+NGrow]; \
    float4 cc0 = cur4[base+2*NGrow]; \
    float4 cp1 = cur4[base+3*NGrow]; \
    float4 cp2 = cur4[base+4*NGrow]; \
    _Pragma("unroll") \
    for (int k = 0; k < 5; ++k) { \
        const int ci = base + (2+k)*NGrow; \
        float4 Lv = cur4[ci - jg + jgm]; \
        float4 Rv = cur4[ci - jg + jgp]; \
        float4 Pp = nxt4[ci]; \
        float4 po; \
        { float lap = C2f*(cm1.x+cp1.x+Lv.w+cc0.y) + C3f*(cm2.x+cp2.x+Lv.z+cc0.z); \
          float t1v = 2.0f + 2.0f*(-2.5f)*Ar[k].x - Kr[k].x; float t0v = 1.0f - Kr[k].x; \
          po.x = Ar[k].x*lap + t1v*cc0.x - t0v*Pp.x; } \
        { float lap = C2f*(cm1.y+cp1.y+cc0.x+cc0.z) + C3f*(cm2.y+cp2.y+Lv.w+cc0.w); \
          float t1v = 2.0f + 2.0f*(-2.5f)*Ar[k].y - Kr[k].y; float t0v = 1.0f - Kr[k].y; \
          po.y = Ar[k].y*lap + t1v*cc0.y - t0v*Pp.y; } \
        { float lap = C2f*(cm1.z+cp1.z+cc0.y+cc0.w) + C3f*(cm2.z+cp2.z+cc0.x+Rv.x); \
          float t1v = 2.0f + 2.0f*(-2.5f)*Ar[k].z - Kr[k].z; float t0v = 1.0f - Kr[k].z; \
          po.z = Ar[k].z*lap + t1v*cc0.z - t0v*Pp.z; } \
        { float lap = C2f*(cm1.w+cp1.w+cc0.z+Rv.x) + C3f*(cm2.w+cp2.w+cc0.y+Rv.y); \
          float t1v = 2.0f + 2.0f*(-2.5f)*Ar[k].w - Kr[k].w; float t0v = 1.0f - Kr[k].w; \
          po.w = Ar[k].w*lap + t1v*cc0.w - t0v*Pp.w; } \
        if (k == qrow) { float add = betaV*srcT; \
            po.x += (qcomp==0)?add:0.0f; po.y += (qcomp==1)?add:0.0f; \
            po.z += (qcomp==2)?add:0.0f; po.w += (qcomp==3)?add:0.0f; } \
        nxt4[ci] = po; \
        if (DOHALO) { \
            if (s == 0 && k < 2) store4_sys(myHalo + hsOff + k*NXx + jg*4, po); \
            if (s == 8 && k >= 3) store4_sys(myHalo + hsOff + (k-1)*NXx + jg*4, po); \
        } \
        cm2 = cm1; cm1 = cc0; cc0 = cp1; cp1 = cp2; \
        if (k < 4) cp2 = cur4[base + (5+k)*NGrow]; \
    } }

    for (int t = 0; t < NSTEPSc; ++t) {
        const int slot = t & 1;
        const int hs   = (t+1) & 3;
        const int hsOff = hs*4*NXx;
        float* cur = (slot == 0) ? buf0 : buf1;
        float* nxt = (slot == 0) ? buf1 : buf0;
        const float4* cur4 = (const float4*)cur;
        float4* nxt4 = (float4*)nxt;
        const float srcT = src[t];

        // ---- phase A: edge strips (rows 0-4, 40-44), publish halo rows ----
        if (isEdge) {
            STRIP_COMPUTE(1)
            drain_vm();   // halo stores acked at coherence point before barrier
        }
        __syncthreads();
        if (tid == 0) storei_sys(flags + b, t + 1);

        // ---- phase B: interior strips — hides flag propagation ----
        if (isStrip && !isEdge) {
            STRIP_COMPUTE(0)
        }

        // ---- phase C: wait for neighbors' field t+1 halos ----
        if (tid == 0) {
            int g = 0;
            while (loadi_sys(flags + up) <= t)
                { __builtin_amdgcn_s_sleep(1); if (++g > 200000) break; }
        }
        if (tid == 64) {
            int g = 0;
            while (loadi_sys(flags + dn) <= t)
                { __builtin_amdgcn_s_sleep(1); if (++g > 200000) break; }
        }
        __syncthreads();

        // ---- phase D: pull halos of field t+1 into nxt rows {0,1,47,48} ----
        if (tid < 4*NGrow) {
            int rr = tid / NGrow, jgq = tid - rr*NGrow;
            const float* sp = (rr < 2) ? (upHalo + (hsOff + (2+rr)*NXx) + jgq*4)
                                       : (dnHalo + (hsOff + (rr-2)*NXx) + jgq*4);
            float4 hv = load4_sys(sp);
            int ldr = (rr < 2) ? rr : (45 + rr);    // 0,1,47,48
            *(float4*)(nxt + ldr*NXx + jgq*4) = hv;
        }

        // ---- phase E: receiver gather for step t (field t+1, from LDS) ----
        if (mOwn) outP[(size_t)t*NMEASc] = nxt[mOff];

        __syncthreads();
    }
#undef STRIP_COMPUTE
}

extern "C" void kernel_launch(void* const* d_in, const int* in_sizes, int n_in,
                              void* d_out, int out_size, void* d_ws, size_t ws_size,
                              hipStream_t stream) {
    const float* v = (const float*)d_in[0];
    float* out = (float*)d_out;

    // workspace layout: haloG first (16B-aligned for dwordx4)
    float* haloG  = (float*)d_ws;                       // NBLK*HALO_PER
    float* alpha  = haloG + (size_t)NBLK*HALO_PER;      // 129600
    float* kap    = alpha + NXY;                        // 129600
    float* beta   = kap + NXY;                          // 32
    float* velmin = beta + NTRc;                        // 1
    float* src_d  = velmin + 1;                         // 640
    int*   meas_d = (int*)(src_d + NSTEPSc);            // 256
    int*   in_d   = meas_d + NMEASc;                    // 32
    int*   flags  = in_d + NTRc;                        // 256

    static int   h_tab[NMEASc + NTRc];
    static float h_src[NSTEPSc];
    {
        const double step = 2.0*M_PI/256.0;
        for (int k = 0; k < NMEASc; ++k) {
            double th = (double)k * step;
            int ti0 = (int)floor(160.0*cos(th) + 179.5);
            int ti1 = (int)floor(160.0*sin(th) + 179.5);
            h_tab[k] = NXx*ti0 + ti1;
        }
        for (int r = 0; r < NTRc; ++r) h_tab[NMEASc + r] = h_tab[r*(NMEASc/NTRc)];
        for (int t = 0; t < NSTEPSc; ++t) {
            double tt = (double)t * 0.2;
            double d  = tt - 3.2;
            double e  = exp(-(d*d) / 288.0);
            double s  = sin(6.283185307179586 * tt);
            h_src[t] = (float)(e * s);
        }
    }
    (void)hipMemcpyAsync(meas_d, h_tab, sizeof(int)*(NMEASc+NTRc), hipMemcpyHostToDevice, stream);
    (void)hipMemcpyAsync(src_d, h_src, sizeof(float)*NSTEPSc, hipMemcpyHostToDevice, stream);
    (void)hipMemsetAsync(haloG, 0, sizeof(float)*(size_t)NBLK*HALO_PER, stream);
    (void)hipMemsetAsync(flags, 0, sizeof(int)*NBLK, stream);

    velmin_kernel<<<1, 256, 0, stream>>>(v, velmin);
    coef_kernel<<<(NXY+255)/256, 256, 0, stream>>>(v, velmin, alpha, kap);
    beta_kernel<<<1, 64, 0, stream>>>(v, in_d, beta);

    (void)hipFuncSetAttribute((const void*)persist_kernel,
                        hipFuncAttributeMaxDynamicSharedMemorySize, LDSFLOATS*4);

    persist_kernel<<<NBLK, NTHREADS, LDSFLOATS*4, stream>>>(
        alpha, kap, beta, src_d, meas_d, in_d, flags, haloG, out);
}